// Round 1
// 143.783 us; speedup vs baseline: 1.0360x; 1.0360x over previous
//
#include <hip/hip_runtime.h>
#include <math.h>

#define J 25
#define NJC 75             // J * CIN
#define NWAVE 4            // waves per block
#define NTHREADS 256
#define NFPW 16            // frames per wave, processed as ILP pairs
#define FRSZ 1056          // bf16 per staged-X region
#define SCRW (4 * FRSZ)    // 4 regions per wave (pair double-buffer)

// const-image layout (bf16 element offsets in CWS, per block in LDS)
#define O_A1T  0           // B for P1, natural k, 1024
#define O_APP  1024        // B for P4, k32-permuted, 1024
#define O_A4B  2048        // A for P7, k32-permuted, 1024
#define O_W2T  3072        // B for P3, k64-permuted, 2048
#define O_W3T  5120        // A for P5, k32-permuted, 2 M-tiles, 2048
#define O_W1T  7168        // A for P2, padded [tt][half][m][c8], half1=0, 1024
#define O_W4C  8192        // B for P6, k64-permuted, [c][b][j], 256
#define O_B4   8512        // 4 floats (8 bf16 slots)
#define O_BPPF 8576        // 64 fp32 bias in C-reg order [g(4)][half(2)][jj(8)]
#define CWS_SZ 8704

using bf16x2 = __attribute__((ext_vector_type(2))) __bf16;
using bf16x8 = __attribute__((ext_vector_type(8))) __bf16;
using f32x4  = __attribute__((ext_vector_type(4))) float;
using f32x16 = __attribute__((ext_vector_type(16))) float;

__device__ inline bf16x8 zero8() {
    bf16x8 z;
    #pragma unroll
    for (int j = 0; j < 8; j++) z[j] = (__bf16)0.f;
    return z;
}

#if defined(__has_builtin)
#if __has_builtin(__builtin_amdgcn_cvt_pk_bf16_f32)
#define HAVE_PK_BF16 1
#endif
#endif

__device__ inline bf16x2 cvt2(float a, float b) {
#ifdef HAVE_PK_BF16
    return __builtin_amdgcn_cvt_pk_bf16_f32(a, b);
#else
    bf16x2 r; r[0] = (__bf16)a; r[1] = (__bf16)b; return r;
#endif
}
__device__ inline bf16x8 pk8(const f32x16& acc, int st) {
    const int b = 8 * st;
    bf16x8 r;
    #pragma unroll
    for (int p = 0; p < 4; p++) {
        bf16x2 v = cvt2(acc[b + 2 * p], acc[b + 2 * p + 1]);
        r[2 * p] = v[0]; r[2 * p + 1] = v[1];
    }
    return r;
}

// ---------------------------------------------------------------------------
// Single self-contained kernel.
// Per-block prologue rebuilds the const image (softmax(A1..A4), App=A3s@A2s,
// bpp=W3^T b2+b3, bf16 frag tables with K-permutations baked in) in LDS,
// overlaying the scratch float tables on the X-staging region (reused after
// the final barrier).  Main loop: TWO independent frames interleaved per wave
// (the P1..P7 chain is latency-bound at ~2 waves/SIMD occupancy; a/b ILP
// doubles independent MFMA/VALU work per resident wave).  X staging uses 4
// regions per wave = pair-granular double buffering, zero barriers in loop.
//
// mfma_f32_32x32x16_bf16 (verified): A[m][k]: m=lane&31, k=8*(lane>>5)+j+16ks
//   B[k][n]: n=lane&31, same k.  C/D: col(lane)=n, rows = ladder rho.
// ---------------------------------------------------------------------------
__global__ __launch_bounds__(NTHREADS, 2) void gcn_fused(
    const float* __restrict__ x,
    const float* __restrict__ A1, const float* __restrict__ W1, const float* __restrict__ b1,
    const float* __restrict__ A2, const float* __restrict__ W2, const float* __restrict__ b2,
    const float* __restrict__ A3, const float* __restrict__ W3, const float* __restrict__ b3,
    const float* __restrict__ A4, const float* __restrict__ W4, const float* __restrict__ b4,
    float* __restrict__ out)
{
    __shared__ __align__(16) __bf16 SCR[NWAVE * SCRW];   // 33792 B
    __shared__ __align__(16) __bf16 CWS[CWS_SZ];         // 17408 B

    const int t = threadIdx.x;

    // ================= per-block prologue: const image into CWS ===========
    {
        float* T   = (float*)SCR;       // 3125 floats, overlays X staging
        float* bpp = T + 3125;          // 64 floats
        float* T0 = T;        float* T1 = T + 625;  float* T2 = T + 1250;
        float* T3 = T + 1875; float* T4 = T + 2500;

        if (t < 100) {
            const int m = t / J, i = t % J;
            const float* Asrc = (m == 0) ? A1 : (m == 1) ? A2 : (m == 2) ? A3 : A4;
            float row[J];
            float mx = -1e30f;
            #pragma unroll
            for (int j = 0; j < J; j++) { row[j] = Asrc[i * J + j]; mx = fmaxf(mx, row[j]); }
            float s = 0.f;
            #pragma unroll
            for (int j = 0; j < J; j++) { row[j] = __expf(row[j] - mx); s += row[j]; }
            const float inv = 1.f / s;
            float* dst = T + m * 625 + i * J;
            #pragma unroll
            for (int j = 0; j < J; j++) dst[j] = row[j] * inv;
        }
        if (t < 64) {                                      // bpp = W3^T b2 + b3
            float s = b3[t];
            #pragma unroll
            for (int l = 0; l < 32; l++) s += W3[l * 64 + t] * b2[l];
            bpp[t] = s;
        }
        __syncthreads();

        for (int idx = t; idx < 625; idx += 256) {        // App = A3s @ A2s
            const int i = idx / J, jj = idx % J;
            float s = 0.f;
            #pragma unroll
            for (int k = 0; k < J; k++) s += T2[i * J + k] * T1[k * J + jj];
            T4[idx] = s;
        }
        __syncthreads();

        // ---- A1T (natural k) | App, A4b (k32-permuted) ----
        for (int i = t; i < 1024; i += 256) {
            const int b = i >> 8, n = (i >> 3) & 31, jj = i & 7;
            const int kn = 8 * b + jj;
            CWS[O_A1T + i] = (__bf16)((kn < J && n < J) ? T0[n * J + kn] : 0.f);
            const int s = b >> 1, h = b & 1, r = 8 * s + jj;
            const int k32 = (r & 3) + 8 * (r >> 2) + 4 * h;
            CWS[O_APP + i] = (__bf16)((k32 < J && n < J) ? T4[n * J + k32] : 0.f);
            CWS[O_A4B + i] = (__bf16)((k32 < J && n < J) ? T3[n * J + k32] : 0.f);
        }
        // ---- W2T (k64-perm) | W3T (k32-perm, 2 tiles) ----
        for (int i = t; i < 2048; i += 256) {
            {
                const int b = i >> 8, n = (i >> 3) & 31, jj = i & 7;
                const int s = b >> 1, h = b & 1, r = 8 * (s & 1) + jj;
                const int d = 32 * (s >> 1) + (r & 3) + 8 * (r >> 2) + 4 * h;
                CWS[O_W2T + i] = (__bf16)W2[d * 32 + n];
            }
            {
                const int tt = i >> 10, rr = i & 1023;
                const int b = rr >> 8, m = (rr >> 3) & 31, jj = rr & 7;
                const int s = b >> 1, h = b & 1, r = 8 * s + jj;
                const int l = (r & 3) + 8 * (r >> 2) + 4 * h;
                CWS[O_W3T + i] = (__bf16)W3[l * 64 + tt * 32 + m];
            }
        }
        // ---- W1T (padded, half1=0, b1 in c=3) ----
        for (int i = t; i < 1024; i += 256) {
            const int tt = i >> 9, rq = i & 511, hf = rq >> 8, q = rq & 255;
            const int m = q >> 3, c = q & 7, d = tt * 32 + m;
            float v = 0.f;
            if (hf == 0) {
                if (c < 3) v = W1[c * 64 + d];
                else if (c == 3) v = b1[d];
            }
            CWS[O_W1T + i] = (__bf16)v;
        }
        // ---- W4c (k64-perm): [c][b][j] = W4[d64][c] ----
        {
            const int c = t >> 6, b = (t >> 3) & 7, jj = t & 7;
            const int s = b >> 1, h = b & 1, r = 8 * (s & 1) + jj;
            const int d = 32 * (s >> 1) + (r & 3) + 8 * (r >> 2) + 4 * h;
            CWS[O_W4C + t] = (c < 3) ? (__bf16)W4[d * 3 + c] : (__bf16)0.f;
        }
        // ---- fp32 bias tables ----
        {
            float* fwB = (float*)(CWS + O_BPPF);
            if (t < 64) {
                const int g = t >> 4, h = (t >> 3) & 1, jj = t & 7;
                const int tt = g >> 1, st = g & 1;
                const int row32 = (jj & 3) + 16 * st + 8 * (jj >> 2) + 4 * h;
                fwB[t] = bpp[tt * 32 + row32];
            }
            float* fb4 = (float*)(CWS + O_B4);
            if (t >= 64 && t < 68) fb4[t - 64] = (t < 67) ? b4[t - 64] : 0.f;
        }
        __syncthreads();   // CWS final; SCR free for X staging
    }

    // ================= main fused pipeline ================================
    const int w = t >> 6, lane = t & 63, ln = lane & 31, half = lane >> 5;
    const int fo = ln * 8;
    __bf16* scr = &SCR[w * SCRW];       // four 1056-el X regions

    const long fbase = ((long)blockIdx.x * NWAVE + w) * NFPW;

    // ---- one-time X-region constants in ALL 4 regions
    #pragma unroll
    for (int r = 0; r < 4; r++) {
        __bf16* s = scr + r * FRSZ;
        if (half == 0) s[(ln >> 3) * 264 + 24 + (ln & 7)] = (ln < J) ? (__bf16)1.f : (__bf16)0.f;
        if (lane < 21) s[3 * 264 + (lane / 7) * 8 + 1 + (lane % 7)] = (__bf16)0.f;
    }

    // X scatter coords: element i -> A[c=i%3][k=i/3]
    const int c0 = lane % 3, j0 = lane / 3;
    const int sx0 = (j0 >> 3) * 264 + c0 * 8 + (j0 & 7);
    const int i1 = 64 + lane, c1 = i1 % 3, j1 = i1 / 3;
    const int sx1 = (j1 >> 3) * 264 + c1 * 8 + (j1 & 7);

    // ---- prologue: stage frames 0,1 into regions 0,1; frames 2,3 -> regs
    #pragma unroll
    for (int u = 0; u < 2; u++) {
        const long xb = (fbase + u) * NJC;
        __bf16* s = scr + u * FRSZ;
        s[sx0] = (__bf16)x[xb + lane];
        if (lane < NJC - 64) s[sx1] = (__bf16)x[xb + 64 + lane];
    }
    float nx0a = 0.f, nx1a = 0.f, nx0b = 0.f, nx1b = 0.f;
    if (NFPW > 2) {
        const long xb2 = (fbase + 2) * NJC;
        nx0a = x[xb2 + lane];
        if (lane < NJC - 64) nx1a = x[xb2 + 64 + lane];
        const long xb3 = (fbase + 3) * NJC;
        nx0b = x[xb3 + lane];
        if (lane < NJC - 64) nx1b = x[xb3 + 64 + lane];
    }

    // ---- register frag loads (once per wave, from block-local LDS image)
    bf16x8 rA1T[2], rApp[2], rA4b[2], rW1[2], rW2[4], rW3[4], rW4[4];
    #pragma unroll
    for (int ks = 0; ks < 2; ks++) {
        rA1T[ks] = *(const bf16x8*)&CWS[O_A1T + (2 * ks + half) * 256 + fo];
        rApp[ks] = *(const bf16x8*)&CWS[O_APP + (2 * ks + half) * 256 + fo];
        rA4b[ks] = *(const bf16x8*)&CWS[O_A4B + (2 * ks + half) * 256 + fo];
        rW1[ks]  = *(const bf16x8*)&CWS[O_W1T + ks * 512 + half * 256 + fo];
    }
    #pragma unroll
    for (int ks = 0; ks < 4; ks++)
        rW2[ks] = *(const bf16x8*)&CWS[O_W2T + (half + 2 * ks) * 256 + fo];
    #pragma unroll
    for (int tt = 0; tt < 2; tt++)
        #pragma unroll
        for (int ks = 0; ks < 2; ks++)
            rW3[tt * 2 + ks] = *(const bf16x8*)&CWS[O_W3T + tt * 1024 + (half + 2 * ks) * 256 + fo];
    #pragma unroll
    for (int ks = 0; ks < 4; ks++) {
        rW4[ks] = zero8();
        if (ln < 3) rW4[ks] = *(const bf16x8*)&CWS[O_W4C + ln * 64 + (half + 2 * ks) * 8];
    }
    f32x4 rBq[8];
    {
        const float* fwB = (const float*)(CWS + O_BPPF);
        #pragma unroll
        for (int g = 0; g < 4; g++)
            #pragma unroll
            for (int p = 0; p < 2; p++)
                rBq[g * 2 + p] = *(const f32x4*)&fwB[(g * 2 + half) * 8 + 4 * p];
    }
    float b4v = 0.f;
    if (ln < 3) b4v = ((const float*)(CWS + O_B4))[ln];

    // ---- shared zero accumulator (MFMA allows D != C)
    f32x16 Z;
    #pragma unroll
    for (int z = 0; z < 16; z++) Z[z] = 0.f;

    for (int fi = 0; fi < NFPW; fi += 2) {
        const long fA = fbase + fi;
        const int pcur = (fi >> 1) & 1;
        __bf16* scA = scr + pcur * (2 * FRSZ);
        __bf16* scB = scA + FRSZ;

        // ---- stage next pair into ALTERNATE regions (overlaps compute)
        if (fi + 2 < NFPW) {
            __bf16* snA = scr + (pcur ^ 1) * (2 * FRSZ);
            __bf16* snB = snA + FRSZ;
            snA[sx0] = (__bf16)nx0a;
            if (lane < NJC - 64) snA[sx1] = (__bf16)nx1a;
            snB[sx0] = (__bf16)nx0b;
            if (lane < NJC - 64) snB[sx1] = (__bf16)nx1b;
        }
        // ---- prefetch pair fi+4, fi+5
        if (fi + 4 < NFPW) {
            const long xbA = (fA + 4) * NJC;
            nx0a = x[xbA + lane];
            if (lane < NJC - 64) nx1a = x[xbA + 64 + lane];
            const long xbB = (fA + 5) * NJC;
            nx0b = x[xbB + lane];
            if (lane < NJC - 64) nx1b = x[xbB + 64 + lane];
        }

        // ==== P1: Y^T = Xaug^T @ A1T (both frames) ====
        bf16x8 a0A = *(const bf16x8*)&scA[half * 264 + fo];
        bf16x8 a1A = *(const bf16x8*)&scA[(2 + half) * 264 + fo];
        bf16x8 a0B = *(const bf16x8*)&scB[half * 264 + fo];
        bf16x8 a1B = *(const bf16x8*)&scB[(2 + half) * 264 + fo];
        f32x16 accYA = __builtin_amdgcn_mfma_f32_32x32x16_bf16(a0A, rA1T[0], Z, 0, 0, 0);
        f32x16 accYB = __builtin_amdgcn_mfma_f32_32x32x16_bf16(a0B, rA1T[0], Z, 0, 0, 0);
        accYA = __builtin_amdgcn_mfma_f32_32x32x16_bf16(a1A, rA1T[1], accYA, 0, 0, 0);
        accYB = __builtin_amdgcn_mfma_f32_32x32x16_bf16(a1B, rA1T[1], accYB, 0, 0, 0);

        // ==== P2: H^T = relu(W1 @ Y^T) ====
        bf16x8 ybA = zero8(), ybB = zero8();
        if (half == 0) {
            bf16x2 q0 = cvt2(accYA[0], accYA[1]);
            bf16x2 q1 = cvt2(accYA[2], accYA[3]);
            ybA[0] = q0[0]; ybA[1] = q0[1]; ybA[2] = q1[0]; ybA[3] = q1[1];
            q0 = cvt2(accYB[0], accYB[1]);
            q1 = cvt2(accYB[2], accYB[3]);
            ybB[0] = q0[0]; ybB[1] = q0[1]; ybB[2] = q1[0]; ybB[3] = q1[1];
        }
        bf16x8 hfA[4], hfB[4];
        #pragma unroll
        for (int tt = 0; tt < 2; tt++) {
            f32x16 aA = __builtin_amdgcn_mfma_f32_32x32x16_bf16(rW1[tt], ybA, Z, 0, 0, 0);
            f32x16 aB = __builtin_amdgcn_mfma_f32_32x32x16_bf16(rW1[tt], ybB, Z, 0, 0, 0);
            #pragma unroll
            for (int z = 0; z < 16; z++) { aA[z] = fmaxf(aA[z], 0.f); aB[z] = fmaxf(aB[z], 0.f); }
            hfA[2 * tt]     = pk8(aA, 0);
            hfA[2 * tt + 1] = pk8(aA, 1);
            hfB[2 * tt]     = pk8(aB, 0);
            hfB[2 * tt + 1] = pk8(aB, 1);
        }

        // ==== P3: U = H @ W2  (K=64) ====
        f32x16 accUA = __builtin_amdgcn_mfma_f32_32x32x16_bf16(hfA[0], rW2[0], Z, 0, 0, 0);
        f32x16 accUB = __builtin_amdgcn_mfma_f32_32x32x16_bf16(hfB[0], rW2[0], Z, 0, 0, 0);
        #pragma unroll
        for (int s = 1; s < 4; s++) {
            accUA = __builtin_amdgcn_mfma_f32_32x32x16_bf16(hfA[s], rW2[s], accUA, 0, 0, 0);
            accUB = __builtin_amdgcn_mfma_f32_32x32x16_bf16(hfB[s], rW2[s], accUB, 0, 0, 0);
        }
        bf16x8 ufA[2] = { pk8(accUA, 0), pk8(accUA, 1) };
        bf16x8 ufB[2] = { pk8(accUB, 0), pk8(accUB, 1) };

        // ==== P4: V = App @ U ====
        f32x16 accVA = __builtin_amdgcn_mfma_f32_32x32x16_bf16(ufA[0], rApp[0], Z, 0, 0, 0);
        f32x16 accVB = __builtin_amdgcn_mfma_f32_32x32x16_bf16(ufB[0], rApp[0], Z, 0, 0, 0);
        accVA = __builtin_amdgcn_mfma_f32_32x32x16_bf16(ufA[1], rApp[1], accVA, 0, 0, 0);
        accVB = __builtin_amdgcn_mfma_f32_32x32x16_bf16(ufB[1], rApp[1], accVB, 0, 0, 0);
        bf16x8 vfA[2] = { pk8(accVA, 0), pk8(accVA, 1) };
        bf16x8 vfB[2] = { pk8(accVB, 0), pk8(accVB, 1) };

        // ==== P5: HD^T = relu(W3 @ V^T + bpp) ====
        bf16x8 hdA[4], hdB[4];
        #pragma unroll
        for (int tt = 0; tt < 2; tt++) {
            f32x16 aA = __builtin_amdgcn_mfma_f32_32x32x16_bf16(rW3[tt * 2 + 0], vfA[0], Z, 0, 0, 0);
            f32x16 aB = __builtin_amdgcn_mfma_f32_32x32x16_bf16(rW3[tt * 2 + 0], vfB[0], Z, 0, 0, 0);
            aA = __builtin_amdgcn_mfma_f32_32x32x16_bf16(rW3[tt * 2 + 1], vfA[1], aA, 0, 0, 0);
            aB = __builtin_amdgcn_mfma_f32_32x32x16_bf16(rW3[tt * 2 + 1], vfB[1], aB, 0, 0, 0);
            #pragma unroll
            for (int st = 0; st < 2; st++) {
                const int g = 2 * tt + st;
                #pragma unroll
                for (int jj = 0; jj < 8; jj++) {
                    aA[8 * st + jj] = fmaxf(aA[8 * st + jj] + rBq[g * 2 + (jj >> 2)][jj & 3], 0.f);
                    aB[8 * st + jj] = fmaxf(aB[8 * st + jj] + rBq[g * 2 + (jj >> 2)][jj & 3], 0.f);
                }
                hdA[g] = pk8(aA, st);
                hdB[g] = pk8(aB, st);
            }
        }

        // ==== P6: P = HD @ W4  (K=64) ====
        f32x16 accPA = __builtin_amdgcn_mfma_f32_32x32x16_bf16(hdA[0], rW4[0], Z, 0, 0, 0);
        f32x16 accPB = __builtin_amdgcn_mfma_f32_32x32x16_bf16(hdB[0], rW4[0], Z, 0, 0, 0);
        #pragma unroll
        for (int s = 1; s < 4; s++) {
            accPA = __builtin_amdgcn_mfma_f32_32x32x16_bf16(hdA[s], rW4[s], accPA, 0, 0, 0);
            accPB = __builtin_amdgcn_mfma_f32_32x32x16_bf16(hdB[s], rW4[s], accPB, 0, 0, 0);
        }
        bf16x8 pfA[2] = { pk8(accPA, 0), pk8(accPA, 1) };
        bf16x8 pfB[2] = { pk8(accPB, 0), pk8(accPB, 1) };

        // ==== P7: out = A4 @ P + b4 ====
        f32x16 accOA = __builtin_amdgcn_mfma_f32_32x32x16_bf16(rA4b[0], pfA[0], Z, 0, 0, 0);
        f32x16 accOB = __builtin_amdgcn_mfma_f32_32x32x16_bf16(rA4b[0], pfB[0], Z, 0, 0, 0);
        accOA = __builtin_amdgcn_mfma_f32_32x32x16_bf16(rA4b[1], pfA[1], accOA, 0, 0, 0);
        accOB = __builtin_amdgcn_mfma_f32_32x32x16_bf16(rA4b[1], pfB[1], accOB, 0, 0, 0);
        if (ln < 3) {
            const long obA = fA * NJC, obB = obA + NJC;
            #pragma unroll
            for (int r = 0; r < 16; r++) {
                const int row = (r & 3) + 8 * (r >> 2) + 4 * half;
                if (row < J) {
                    out[obA + row * 3 + ln] = accOA[r] + b4v;
                    out[obB + row * 3 + ln] = accOB[r] + b4v;
                }
            }
        }
    }
}

// ---------------------------------------------------------------------------
extern "C" void kernel_launch(void* const* d_in, const int* in_sizes, int n_in,
                              void* d_out, int out_size, void* d_ws, size_t ws_size,
                              hipStream_t stream)
{
    const float* x  = (const float*)d_in[0];
    const float* A1 = (const float*)d_in[1];
    const float* W1 = (const float*)d_in[2];
    const float* b1 = (const float*)d_in[3];
    const float* A2 = (const float*)d_in[4];
    const float* W2 = (const float*)d_in[5];
    const float* b2 = (const float*)d_in[6];
    const float* A3 = (const float*)d_in[7];
    const float* W3 = (const float*)d_in[8];
    const float* b3 = (const float*)d_in[9];
    const float* A4 = (const float*)d_in[10];
    const float* W4 = (const float*)d_in[11];
    const float* b4 = (const float*)d_in[12];
    float* out = (float*)d_out;
    (void)d_ws; (void)ws_size;

    const int NT = in_sizes[0] / NJC;                 // 65536
    const int nblocks = NT / (NWAVE * NFPW);          // 1024

    gcn_fused<<<nblocks, NTHREADS, 0, stream>>>(
        x, A1, W1, b1, A2, W2, b2, A3, W3, b3, A4, W4, b4, out);
}